// Round 13
// baseline (800.728 us; speedup 1.0000x reference)
//
#include <hip/hip_runtime.h>
#include <cstdint>
#include <cstddef>

typedef unsigned int u32;
typedef unsigned long long u64;
typedef __attribute__((ext_vector_type(8))) short s8v;   // 8 bf16 (4 VGPRs)
typedef __attribute__((ext_vector_type(4))) float f4v;   // MFMA C/D
typedef __attribute__((ext_vector_type(4))) unsigned short us4;

#define B_   2
#define L_   2048
#define D_   1024
#define NH_  16
#define KVH_ 8
#define DH_  64
#define TOPK_ 1024

#define MFMA16(a, b, c) __builtin_amdgcn_mfma_f32_16x16x32_bf16(a, b, c, 0, 0, 0)

// order-preserving float->uint key (descending float == descending uint)
__device__ __forceinline__ u32 fkey(float s) {
    u32 b = __float_as_uint(s);
    return b ^ ((u32)((int)b >> 31) | 0x80000000u);
}
// exact inverse of fkey
__device__ __forceinline__ float fkeyinv(u32 k) {
    u32 b = (k & 0x80000000u) ? (k ^ 0x80000000u) : ~k;
    return __uint_as_float(b);
}
// fp32 -> bf16 round-to-nearest-even, as raw ushort
__device__ __forceinline__ unsigned short bf16rne(float x) {
    u32 u = __float_as_uint(x);
    u32 r = (u + 0x7FFFu + ((u >> 16) & 1u)) >> 16;
    return (unsigned short)r;
}
__device__ __forceinline__ float bf2f(unsigned short h) {
    return __uint_as_float((u32)h << 16);
}

// ---------------------------------------------------------------------------
// All weight preps in ONE launch. grid (16, 48): by<16 wq -> QKVW rows 0..1023,
// 16..23 wk -> rows 1024..1535, 24..31 wv -> rows 1536..2047, 32..47 wo -> Wo.
// W [K=1024][N] fp32 -> dest [row][1024] bf16 hi/lo (transpose + split).
// ---------------------------------------------------------------------------
__global__ __launch_bounds__(256) void prep_wt_all(
    const float* __restrict__ wq, const float* __restrict__ wk,
    const float* __restrict__ wv, const float* __restrict__ wo,
    unsigned short* __restrict__ QKVWh, unsigned short* __restrict__ QKVWl,
    unsigned short* __restrict__ WoH, unsigned short* __restrict__ WoL) {
    __shared__ float tile[64 * 65];
    const int k0 = blockIdx.x * 64;
    const int byy = blockIdx.y;
    const float* W;
    unsigned short *Dh, *Dl;
    int N, n0, nrow;
    if (byy < 16)      { W = wq; N = 1024; n0 = byy * 64;        Dh = QKVWh; Dl = QKVWl; nrow = byy * 64; }
    else if (byy < 24) { W = wk; N = 512;  n0 = (byy - 16) * 64; Dh = QKVWh; Dl = QKVWl; nrow = 1024 + (byy - 16) * 64; }
    else if (byy < 32) { W = wv; N = 512;  n0 = (byy - 24) * 64; Dh = QKVWh; Dl = QKVWl; nrow = 1536 + (byy - 24) * 64; }
    else               { W = wo; N = 1024; n0 = (byy - 32) * 64; Dh = WoH;   Dl = WoL;   nrow = (byy - 32) * 64; }
    int t = threadIdx.x;
#pragma unroll
    for (int i = 0; i < 16; ++i) {
        int idx = t + i * 256;
        int kk = idx >> 6, nn = idx & 63;
        tile[kk * 65 + nn] = W[(size_t)(k0 + kk) * N + n0 + nn];
    }
    __syncthreads();
#pragma unroll
    for (int i = 0; i < 16; ++i) {
        int idx = t + i * 256;
        int nn = idx >> 6, kk = idx & 63;
        float x = tile[kk * 65 + nn];
        unsigned short hi = bf16rne(x);
        unsigned short lo = bf16rne(x - bf2f(hi));
        Dh[(size_t)(nrow + nn) * 1024 + k0 + kk] = hi;
        Dl[(size_t)(nrow + nn) * 1024 + k0 + kk] = lo;
    }
}

// ---------------------------------------------------------------------------
// A [M][K] fp32 -> AH/AL bf16 hi/lo (same layout). 4 elems/thread.
// ---------------------------------------------------------------------------
__global__ __launch_bounds__(256) void split_a(const float* __restrict__ A,
                                               unsigned short* __restrict__ AH,
                                               unsigned short* __restrict__ AL) {
    size_t tid = (size_t)blockIdx.x * 256 + threadIdx.x;
    float4 v = *(const float4*)(A + tid * 4);
    us4 hv, lv;
    float x[4] = {v.x, v.y, v.z, v.w};
#pragma unroll
    for (int i = 0; i < 4; ++i) {
        unsigned short hi = bf16rne(x[i]);
        hv[i] = hi;
        lv[i] = bf16rne(x[i] - bf2f(hi));
    }
    *(us4*)(AH + tid * 4) = hv;
    *(us4*)(AL + tid * 4) = lv;
}

// ---------------------------------------------------------------------------
// MFMA GEMM, bf16-A variant: C[M][N] fp32 = A(hi/lo bf16, row stride lda)
// @ Wt([N][K] bf16 hi/lo), 3-term hi/lo. BM=BN=128, BK=32; 256 thr.
// grid (M/128, N/128), XCD-chunked swizzle (nwg%8==0).
// ---------------------------------------------------------------------------
__global__ __launch_bounds__(256) void gemm_bf(
    const unsigned short* __restrict__ Ah,
    const unsigned short* __restrict__ Al,
    int lda,
    const unsigned short* __restrict__ Wh,
    const unsigned short* __restrict__ Wl,
    float* __restrict__ C, int K, int N) {
    __shared__ __align__(16) unsigned short lAh[128 * 40];
    __shared__ __align__(16) unsigned short lAl[128 * 40];
    __shared__ __align__(16) unsigned short lBh[128 * 40];
    __shared__ __align__(16) unsigned short lBl[128 * 40];
    const int t = threadIdx.x, lane = t & 63, w = t >> 6;
    const int quad = lane >> 4, col = lane & 15;
    const int wm = w >> 1, wn = w & 1;
    const int nwg = gridDim.x * gridDim.y;
    const int lin = blockIdx.y * gridDim.x + blockIdx.x;
    const int swz = (lin & 7) * (nwg >> 3) + (lin >> 3);
    const int bx = swz % gridDim.x, by = swz / gridDim.x;
    const int m0 = bx * 128, n0 = by * 128;
    const int sr = t >> 1, sk = (t & 1) * 16;

    f4v acc[4][4];
#pragma unroll
    for (int i = 0; i < 4; ++i)
#pragma unroll
        for (int j = 0; j < 4; ++j) acc[i][j] = (f4v){0.f, 0.f, 0.f, 0.f};

    for (int k0 = 0; k0 < K; k0 += 32) {
        const unsigned short* ap = Ah + (size_t)(m0 + sr) * lda + k0 + sk;
        const unsigned short* alp = Al + (size_t)(m0 + sr) * lda + k0 + sk;
        s8v a_h0 = *(const s8v*)(ap);
        s8v a_h1 = *(const s8v*)(ap + 8);
        s8v a_l0 = *(const s8v*)(alp);
        s8v a_l1 = *(const s8v*)(alp + 8);
        s8v bh0 = *(const s8v*)(Wh + (size_t)(n0 + sr) * K + k0 + sk);
        s8v bh1 = *(const s8v*)(Wh + (size_t)(n0 + sr) * K + k0 + sk + 8);
        s8v bl0 = *(const s8v*)(Wl + (size_t)(n0 + sr) * K + k0 + sk);
        s8v bl1 = *(const s8v*)(Wl + (size_t)(n0 + sr) * K + k0 + sk + 8);
        __syncthreads();
        *(s8v*)&lAh[sr * 40 + sk]     = a_h0;
        *(s8v*)&lAh[sr * 40 + sk + 8] = a_h1;
        *(s8v*)&lAl[sr * 40 + sk]     = a_l0;
        *(s8v*)&lAl[sr * 40 + sk + 8] = a_l1;
        *(s8v*)&lBh[sr * 40 + sk]     = bh0;
        *(s8v*)&lBh[sr * 40 + sk + 8] = bh1;
        *(s8v*)&lBl[sr * 40 + sk]     = bl0;
        *(s8v*)&lBl[sr * 40 + sk + 8] = bl1;
        __syncthreads();
        s8v amh[4], aml[4], bnh[4], bnl[4];
#pragma unroll
        for (int mt = 0; mt < 4; ++mt) {
            amh[mt] = *(s8v*)&lAh[(wm * 64 + mt * 16 + col) * 40 + quad * 8];
            aml[mt] = *(s8v*)&lAl[(wm * 64 + mt * 16 + col) * 40 + quad * 8];
        }
#pragma unroll
        for (int nt = 0; nt < 4; ++nt) {
            bnh[nt] = *(s8v*)&lBh[(wn * 64 + nt * 16 + col) * 40 + quad * 8];
            bnl[nt] = *(s8v*)&lBl[(wn * 64 + nt * 16 + col) * 40 + quad * 8];
        }
#pragma unroll
        for (int mt = 0; mt < 4; ++mt)
#pragma unroll
            for (int nt = 0; nt < 4; ++nt) {
                acc[mt][nt] = MFMA16(amh[mt], bnh[nt], acc[mt][nt]);
                acc[mt][nt] = MFMA16(amh[mt], bnl[nt], acc[mt][nt]);
                acc[mt][nt] = MFMA16(aml[mt], bnh[nt], acc[mt][nt]);
            }
    }
#pragma unroll
    for (int mt = 0; mt < 4; ++mt)
#pragma unroll
        for (int nt = 0; nt < 4; ++nt)
#pragma unroll
            for (int r = 0; r < 4; ++r)
                C[(size_t)(m0 + wm * 64 + mt * 16 + quad * 4 + r) * N +
                  n0 + wn * 64 + nt * 16 + col] = acc[mt][nt][r];
}

// ---------------------------------------------------------------------------
// RoPE on K + hi/lo bf16 split. K in fused QKV: row stride 2048, col
// 1024 + kvh*64 + d. Output layout [b][kvh][l][d].
// ---------------------------------------------------------------------------
__global__ __launch_bounds__(256) void prep_k(const float* __restrict__ QKV,
                                              unsigned short* __restrict__ KHp,
                                              unsigned short* __restrict__ KLp,
                                              const int* __restrict__ pos) {
    int tid = blockIdx.x * 256 + threadIdx.x;
    int d   = tid & 63;
    int l   = (tid >> 6) & 2047;
    int kvh = (tid >> 17) & 7;
    int b   = tid >> 20;
    size_t src = (size_t)(b * L_ + l) * 2048 + 1024 + kvh * DH_;
    float x  = QKV[src + d];
    int dp   = (d < 32) ? d + 32 : d - 32;
    float xp = QKV[src + dp];
    float p = (float)pos[b * L_ + l];
    int i = d & 31;
    float invf = (float)pow(10000.0, -(double)i / 32.0);
    float a = p * invf;
    float s, c;
    sincosf(a, &s, &c);
    float out = (d < 32) ? (x * c - xp * s) : (x * c + xp * s);
    unsigned short hi = bf16rne(out);
    unsigned short lo = bf16rne(out - bf2f(hi));
    size_t dst = ((size_t)(b * KVH_ + kvh) * L_ + l) * DH_ + d;
    KHp[dst] = hi;
    KLp[dst] = lo;
}

// ---------------------------------------------------------------------------
// V transpose to bf16 from fused QKV (V at col 1536 + kvh*64 + d, stride 2048)
// -> VT[b][kvh][d][l]
// ---------------------------------------------------------------------------
__global__ __launch_bounds__(256) void prep_v(const float* __restrict__ QKV,
                                              unsigned short* __restrict__ VTp) {
    __shared__ float tile[64 * 65];
    int bid = blockIdx.x;
    int lb  = bid & 31;
    int kvh = (bid >> 5) & 7;
    int b   = bid >> 8;
    int l0  = lb * 64;
    int t   = threadIdx.x;
#pragma unroll
    for (int i = 0; i < 16; ++i) {
        int idx = t + i * 256;
        int ll = idx >> 6, d = idx & 63;
        tile[ll * 65 + d] =
            QKV[(size_t)(b * L_ + l0 + ll) * 2048 + 1536 + kvh * DH_ + d];
    }
    __syncthreads();
#pragma unroll
    for (int i = 0; i < 16; ++i) {
        int idx = t + i * 256;
        int d = idx >> 6, ll = idx & 63;
        VTp[((size_t)(b * KVH_ + kvh) * DH_ + d) * L_ + l0 + ll] = bf16rne(tile[ll * 65 + d]);
    }
}

// ---------------------------------------------------------------------------
// Fused sparse attention, R21 = R20 + (a) interleaved dual-row middle and
// (b) RoPE(Q) fused into the Q-tile stage.
// (a) R20's middle(ukA); middle(ukB) share one hist region -> WAR memory dep
//     forbids overlapping their serial shfl chains (6-deep scans ~250cy,
//     butterflies ~500cy). Give each row its own 4x-replicated hist
//     (8 waves x 2 rows x 1KB = 64KB, fits the 66KB Sc U Pc union, same
//     time-multiplexed live range) and run both rows' norm/radix/scan in
//     lockstep -- each chain's latency hides under the other. Per-row state
//     is wave-uniform so early-exit guards are scalar branches. Bit-exact.
// (b) rope in qtile (invf via same double-pow -> bit-identical): kills the
//     rope_q launch + 32MB HBM round trip.
// Watch: WRITE_SIZE >> 26MB -> register-pressure spills from (a), revert.
// ---------------------------------------------------------------------------
__global__ __launch_bounds__(512, 4) void attn(
    const float* __restrict__ QR,
    const unsigned short* __restrict__ KH,
    const unsigned short* __restrict__ KL,
    const unsigned short* __restrict__ VT,
    const int* __restrict__ pos,
    unsigned short* __restrict__ AOus) {

    extern __shared__ __align__(16) unsigned char dynsm[];
    float* Sc = (float*)dynsm;                     // [16][1034] f32 = 66176B
    unsigned short* Pc = (unsigned short*)dynsm;   // [16][2072] us = 66304B (union)
    u32* hist = (u32*)dynsm;                       // [8][2048] u32 = 65536B (union;
                                                   // live between Sc-reads-done
                                                   // and the pre-Pc barrier)
    float* qtile  = (float*)(dynsm + 66304);       // [16][68] f32 = 4352B
    float* outred = (float*)(dynsm + 66304);       // union w/ qtile (dead after A-frags)
    float* ltab   = (float*)(dynsm + 70656);       // [32] f32 rope invf table

    const int t = threadIdx.x;                     // 0..511
    const int lane = t & 63, w = t >> 6;           // w in [0,8)
    const int quad = lane >> 4, col = lane & 15;
    // XCD-chunked remap (bijective: 4096 % 8 == 0)
    const int bid0 = blockIdx.x;
    const int bid  = (bid0 & 7) * 512 + (bid0 >> 3);
    const int l0  = (bid & 255) * 8;
    const int kvh = (bid >> 8) & 7;
    const int b   = bid >> 11;
    const int r0 = 2 * w, r1 = 2 * w + 1;          // q-rows owned by this wave

    // ---- rope invf table (matches rope_q's double-pow exactly)
    if (t < 32) ltab[t] = (float)pow(10000.0, -(double)t / 32.0);

    // ---- load raw Q tile (16 rows = 8 l-pos x heads {2kvh, 2kvh+1})
    if (t < 256) {
        int q = t >> 4, d4 = (t & 15) * 4;
        *(float4*)&qtile[q * 68 + d4] =
            *(const float4*)(QR + (size_t)(b * L_ + l0 + (q & 7)) * 2048 +
                             (kvh * 2 + (q >> 3)) * DH_ + d4);
    }
    __syncthreads();

    // ---- RoPE in LDS: t<128, each handles (q, 4 d's in 0..31)
    if (t < 128) {
        int q = t >> 3, dg = (t & 7) * 4;
        float p = (float)pos[b * L_ + l0 + (q & 7)];
#pragma unroll
        for (int dd = 0; dd < 4; ++dd) {
            int d = dg + dd;
            float x1 = qtile[q * 68 + d];
            float x2 = qtile[q * 68 + d + 32];
            float s, c;
            sincosf(p * ltab[d], &s, &c);
            qtile[q * 68 + d]      = x1 * c - x2 * s;
            qtile[q * 68 + d + 32] = x2 * c + x1 * s;
        }
    }
    __syncthreads();

    // ---- build A-frags (hi/lo): A[m=col][k=ks*32+quad*8+i]; all 16 rows real
    union FR { s8v v; unsigned short u[8]; };
    FR ah[2], al[2];
#pragma unroll
    for (int ks = 0; ks < 2; ++ks)
#pragma unroll
        for (int i = 0; i < 8; ++i) {
            float x = qtile[col * 68 + ks * 32 + quad * 8 + i];
            unsigned short hi = bf16rne(x);
            ah[ks].u[i] = hi;
            al[ks].u[i] = bf16rne(x - bf2f(hi));
        }

    // ---- QK^T in 2 J-halves of 1024 cols (wave slice 128 cols = 8 tj/half)
    const size_t slabK = (size_t)(b * KVH_ + kvh) * L_ * DH_;
    const unsigned short* khp = KH + slabK;
    const unsigned short* klp = KL + slabK;
    u32 ukA[32], ukB[32];   // keys: elem i <-> j = 1024*(i>>4) + 64*(i&15) + lane

#pragma unroll
    for (int half = 0; half < 2; ++half) {
        if (half) __syncthreads();       // half0 reads done before rewrite
#pragma unroll
        for (int tj = 0; tj < 8; ++tj) {
            int jl = w * 128 + tj * 16;  // col within half
            int j0 = half * 1024 + jl;   // global col
            const unsigned short* kh8 = khp + (size_t)(j0 + col) * 64 + quad * 8;
            const unsigned short* kl8 = klp + (size_t)(j0 + col) * 64 + quad * 8;
            s8v bh0 = *(const s8v*)(kh8);
            s8v bh1 = *(const s8v*)(kh8 + 32);
            s8v bl0 = *(const s8v*)(kl8);
            s8v bl1 = *(const s8v*)(kl8 + 32);
            f4v c = {0.f, 0.f, 0.f, 0.f};
            c = MFMA16(ah[0].v, bh0, c);
            c = MFMA16(al[0].v, bh0, c);
            c = MFMA16(ah[0].v, bl0, c);
            c = MFMA16(ah[1].v, bh1, c);
            c = MFMA16(al[1].v, bh1, c);
            c = MFMA16(ah[1].v, bl1, c);
            c = c * 0.125f;              // DH^-0.5
#pragma unroll
            for (int r = 0; r < 4; ++r)
                Sc[(quad * 4 + r) * 1034 + jl + col] = c[r];
        }
        __syncthreads();                 // Sc(half) complete
        if (half == 0) {                 // qtile dead; zero outred (union)
            outred[t] = 0.f;
            outred[t + 512] = 0.f;
            if (t < 64) outred[1024 + t] = 0.f;
        }
#pragma unroll
        for (int i2 = 0; i2 < 16; ++i2) {
            ukA[half * 16 + i2] = fkey(Sc[r0 * 1034 + i2 * 64 + lane]);
            ukB[half * 16 + i2] = fkey(Sc[r1 * 1034 + i2 * 64 + lane]);
        }
    }
    __syncthreads();                     // all Sc reads done; region free (hist)

    // ---- interleaved dual-row middle (norm + radix top-1024 + softmax).
    // Per-row 4x-replicated hist; digit d, replica lane&3 at
    // hq[(d&3)*256 + (d>>2)*4 + (lane&3)]; read = bank-optimal uint4.
    u32* hqA = &hist[w * 2048];
    u32* hqB = &hist[w * 2048 + 1024];
    const int rep = lane & 3;
    float invZA, invZB;
    u32 geqA = 0u, geqB = 0u, uthA, uthB, ngA = 0u, ngB = 0u;
    int shAi, shBi;
    u32 uloA, uloB;
    float mrowA, mrowB;
    {
        // normalization, both rows interleaved
        u32 loA = 0xFFFFFFFFu, hiA = 0u, loB = 0xFFFFFFFFu, hiB = 0u;
#pragma unroll
        for (int i = 0; i < 32; ++i) {
            u32 a = ukA[i], bb = ukB[i];
            loA = (a < loA) ? a : loA;  hiA = (a > hiA) ? a : hiA;
            loB = (bb < loB) ? bb : loB; hiB = (bb > hiB) ? bb : hiB;
        }
        for (int off = 1; off < 64; off <<= 1) {
            u32 xa = (u32)__shfl_xor((int)loA, off);
            u32 ya = (u32)__shfl_xor((int)hiA, off);
            u32 xb = (u32)__shfl_xor((int)loB, off);
            u32 yb = (u32)__shfl_xor((int)hiB, off);
            loA = (xa < loA) ? xa : loA;  hiA = (ya > hiA) ? ya : hiA;
            loB = (xb < loB) ? xb : loB;  hiB = (yb > hiB) ? yb : hiB;
        }
        mrowA = fkeyinv(hiA); mrowB = fkeyinv(hiB);
        shAi = __clz((int)((hiA - loA) | 1u));
        shBi = __clz((int)((hiB - loB) | 1u));
        uloA = loA; uloB = loB;
#pragma unroll
        for (int i = 0; i < 32; ++i) {
            ukA[i] = (ukA[i] - loA) << shAi;
            ukB[i] = (ukB[i] - loB) << shBi;
        }

        // radix passes, rows interleaved, per-row early-exit
        u32 pfA = 0u, kqA = (u32)TOPK_;
        u32 pfB = 0u, kqB = (u32)TOPK_;
        u32 doneA = 0u, doneB = 0u;
        for (int pass = 0; pass < 4; ++pass) {
            int shift = 24 - 8 * pass;
            if (!doneA) {
#pragma unroll
                for (int i = 0; i < 4; ++i)
                    *(uint4*)&hqA[i * 256 + lane * 4] = make_uint4(0u, 0u, 0u, 0u);
            }
            if (!doneB) {
#pragma unroll
                for (int i = 0; i < 4; ++i)
                    *(uint4*)&hqB[i * 256 + lane * 4] = make_uint4(0u, 0u, 0u, 0u);
            }
            u32 pm = pass ? (0xFFFFFFFFu << (shift + 8)) : 0u;
#pragma unroll
            for (int i = 0; i < 32; ++i) {
                if (!doneA) {
                    u32 u = ukA[i];
                    if ((u & pm) == pfA) {
                        u32 d = (u >> shift) & 255u;
                        atomicAdd(&hqA[(d & 3) * 256 + (d >> 2) * 4 + rep], 1u);
                    }
                }
                if (!doneB) {
                    u32 u = ukB[i];
                    if ((u & pm) == pfB) {
                        u32 d = (u >> shift) & 255u;
                        atomicAdd(&hqB[(d & 3) * 256 + (d >> 2) * 4 + rep], 1u);
                    }
                }
            }
            // reads (may-alias the atomics => real ds ops, wave-ordered)
            u32 hbA_[4] = {0u, 0u, 0u, 0u}, hbB_[4] = {0u, 0u, 0u, 0u};
            u32 s4A = 0u, s4B = 0u;
            if (!doneA) {
#pragma unroll
                for (int bb = 0; bb < 4; ++bb) {
                    uint4 hv = *(const uint4*)&hqA[bb * 256 + lane * 4];
                    hbA_[bb] = hv.x + hv.y + hv.z + hv.w;
                    s4A += hbA_[bb];
                }
            }
            if (!doneB) {
#pragma unroll
                for (int bb = 0; bb < 4; ++bb) {
                    uint4 hv = *(const uint4*)&hqB[bb * 256 + lane * 4];
                    hbB_[bb] = hv.x + hv.y + hv.z + hv.w;
                    s4B += hbB_[bb];
                }
            }
            // interleaved exclusive scans (two independent shfl chains)
            u32 vA = s4A, vB = s4B;
            for (int off = 1; off < 64; off <<= 1) {
                u32 ta = __shfl_down(vA, off);
                u32 tb = __shfl_down(vB, off);
                if (lane + off < 64) { vA += ta; vB += tb; }
            }
            if (!doneA) {
                u32 g = vA - s4A;
                u32 mydig = 0u, myk = 0u, myng = 0u, myhb = 0u;
                bool found = false;
#pragma unroll
                for (int bb = 3; bb >= 0; --bb) {
                    u32 hb = hbA_[bb];
                    if (hb && g < kqA && kqA <= g + hb) {
                        found = true;
                        mydig = (u32)(4 * lane + bb);
                        myk   = kqA - g;
                        myng  = ngA + g;
                        myhb  = hb;
                    }
                    g += hb;
                }
                u64 fm = __ballot(found);
                int src = (int)__builtin_ctzll(fm);
                pfA |= ((u32)__shfl((int)mydig, src)) << shift;
                kqA  = (u32)__shfl((int)myk,  src);
                ngA  = (u32)__shfl((int)myng, src);
                u32 hbs = (u32)__shfl((int)myhb, src);
                if (kqA == hbs) { geqA = 1u; doneA = 1u; }
            }
            if (!doneB) {
                u32 g = vB - s4B;
                u32 mydig = 0u, myk = 0u, myng = 0u, myhb = 0u;
                bool found = false;
#pragma unroll
                for (int bb = 3; bb >= 0; --bb) {
                    u32 hb = hbB_[bb];
                    if (hb && g < kqB && kqB <= g + hb) {
                        found = true;
                        mydig = (u32)(4 * lane + bb);
                        myk   = kqB - g;
                        myng  = ngB + g;
                        myhb  = hb;
                    }
                    g += hb;
                }
                u64 fm = __ballot(found);
                int src = (int)__builtin_ctzll(fm);
                pfB |= ((u32)__shfl((int)mydig, src)) << shift;
                kqB  = (u32)__shfl((int)myk,  src);
                ngB  = (u32)__shfl((int)myng, src);
                u32 hbs = (u32)__shfl((int)myhb, src);
                if (kqB == hbs) { geqB = 1u; doneB = 1u; }
            }
            if (doneA && doneB) break;
        }
        uthA = pfA; uthB = pfB;
    }

    // ---- selection + softmax per row (short chains; sequential)
    auto finish = [&](u32 (&uk)[32], u32 uth, u32 geq, u32 ng,
                      int sh, u32 ulo, float mrow) -> float {
        u32 selm = 0u;
        if (geq) {
#pragma unroll
            for (int i = 0; i < 32; ++i)
                if (uk[i] >= uth) selm |= 1u << i;
        } else {
            const u32 quota = (u32)TOPK_ - ng;
            u32 eqm = 0u;
#pragma unroll
            for (int i = 0; i < 32; ++i) {
                u32 u = uk[i];
                if (u > uth) selm |= 1u << i;
                else if (u == uth) eqm |= 1u << i;
            }
            u32 ec = (u32)__builtin_popcount(eqm);
            for (int off = 1; off < 64; off <<= 1) ec += __shfl_xor(ec, off);
            if (ec == quota) {
                selm |= eqm;
            } else {
                u32 base = 0;
                u64 lmask = ((u64)1 << lane) - 1;
#pragma unroll
                for (int i = 0; i < 32; ++i) {
                    u64 mm = __ballot((eqm >> i) & 1u);
                    if ((eqm >> i) & 1u) {
                        u32 rk = base + (u32)__builtin_popcountll(mm & lmask);
                        if (rk < quota) selm |= 1u << i;
                    }
                    base += (u32)__builtin_popcountll(mm);
                }
            }
        }
        float z = 0.f;
#pragma unroll
        for (int i = 0; i < 32; ++i) {
            float vv = fkeyinv((uk[i] >> sh) + ulo);      // exact inverse
            float e = ((selm >> i) & 1u) ? __expf(vv - mrow) : 0.f;
            uk[i] = __float_as_uint(e);
            z += e;
        }
        for (int off = 1; off < 64; off <<= 1) z += __shfl_xor(z, off);
        return 1.0f / z;
    };
    invZA = finish(ukA, uthA, geqA, ngA, shAi, uloA, mrowA);
    invZB = finish(ukB, uthB, geqB, ngB, shBi, uloB, mrowB);

    // ---- prefetch kc0 V tiles (L2 loads overlap the barrier + P writes)
    const unsigned short* vt = VT + (size_t)(b * KVH_ + kvh) * DH_ * L_;
    const int jb0 = w * 256 + quad * 8;
    s8v pv0 = *(const s8v*)(vt + (size_t)( 0 + col) * L_ + jb0);
    s8v pv1 = *(const s8v*)(vt + (size_t)(16 + col) * L_ + jb0);
    s8v pv2 = *(const s8v*)(vt + (size_t)(32 + col) * L_ + jb0);
    s8v pv3 = *(const s8v*)(vt + (size_t)(48 + col) * L_ + jb0);

    __syncthreads();                     // all hist use done; Pc region free

    // ---- P -> Pc (bf16, invZ folded); rows r0, r1
#pragma unroll
    for (int i = 0; i < 32; ++i) {
        int jp = 1024 * (i >> 4) + 64 * (i & 15) + lane;
        Pc[r0 * 2072 + jp] = bf16rne(__uint_as_float(ukA[i]) * invZA);
        Pc[r1 * 2072 + jp] = bf16rne(__uint_as_float(ukB[i]) * invZB);
    }
    __syncthreads();                     // all P rows written

    // ---- PV via MFMA; wave w covers j in [256w, 256w+256) in 8 sub-chunks
    f4v acc0 = {0.f, 0.f, 0.f, 0.f}, acc1 = acc0, acc2 = acc0, acc3 = acc0;
    {
        s8v ap = *(const s8v*)&Pc[col * 2072 + jb0];
        acc0 = MFMA16(ap, pv0, acc0);
        acc1 = MFMA16(ap, pv1, acc1);
        acc2 = MFMA16(ap, pv2, acc2);
        acc3 = MFMA16(ap, pv3, acc3);
    }
#pragma unroll
    for (int kc = 1; kc < 8; ++kc) {
        int jb = w * 256 + kc * 32 + quad * 8;
        s8v ap = *(const s8v*)&Pc[col * 2072 + jb];
        s8v v0 = *(const s8v*)(vt + (size_t)( 0 + col) * L_ + jb);
        s8v v1 = *(const s8v*)(vt + (size_t)(16 + col) * L_ + jb);
        s8v v2 = *(const s8v*)(vt + (size_t)(32 + col) * L_ + jb);
        s8v v3 = *(const s8v*)(vt + (size_t)(48 + col) * L_ + jb);
        acc0 = MFMA16(ap, v0, acc0);
        acc1 = MFMA16(ap, v1, acc1);
        acc2 = MFMA16(ap, v2, acc2);
        acc3 = MFMA16(ap, v3, acc3);
    }

    // ---- cross-wave PV reduction (all 16 rows live) + store as bf16 hi/lo
#pragma unroll
    for (int r = 0; r < 4; ++r) {
        atomicAdd(&outred[(quad * 4 + r) * 68 +  0 + col], acc0[r]);
        atomicAdd(&outred[(quad * 4 + r) * 68 + 16 + col], acc1[r]);
        atomicAdd(&outred[(quad * 4 + r) * 68 + 32 + col], acc2[r]);
        atomicAdd(&outred[(quad * 4 + r) * 68 + 48 + col], acc3[r]);
    }
    __syncthreads();
    if (t < 256) {
        int q = t >> 4, d4 = (t & 15) * 4;
        float4 o = *(float4*)&outred[q * 68 + d4];
        size_t m = (size_t)(b * L_ + l0 + (q & 7));
        int n = (kvh * 2 + (q >> 3)) * DH_ + d4;
        float x[4] = {o.x, o.y, o.z, o.w};
        us4 hv, lv;
#pragma unroll
        for (int i = 0; i < 4; ++i) {
            unsigned short hi = bf16rne(x[i]);
            hv[i] = hi;
            lv[i] = bf16rne(x[i] - bf2f(hi));
        }
        *(us4*)(AOus + m * 4096 + 2048 + n) = hv;
        *(us4*)(AOus + m * 4096 + 3072 + n) = lv;
    }
}

// ---------------------------------------------------------------------------
extern "C" void kernel_launch(void* const* d_in, const int* in_sizes, int n_in,
                              void* d_out, int out_size, void* d_ws, size_t ws_size,
                              hipStream_t stream) {
    const float* hs = (const float*)d_in[0];
    const float* wq = (const float*)d_in[1];
    const float* wk = (const float*)d_in[2];
    const float* wv = (const float*)d_in[3];
    const float* wo = (const float*)d_in[4];
    const int*  pos = (const int*)d_in[5];

    float* ws = (float*)d_ws;
    const size_t M1 = 1u << 20;
    float* QKV = ws;                           // [0, 8M) fp32 [4096][2048]
    unsigned short* QKVWh = (unsigned short*)(ws +  8 * M1);  // [2048][1024]
    unsigned short* QKVWl = (unsigned short*)(ws +  9 * M1);
    unsigned short* WoH   = (unsigned short*)(ws + 10 * M1);
    unsigned short* WoL   = (unsigned short*)(ws + 10 * M1 + M1 / 2);
    unsigned short* KH    = (unsigned short*)(ws + 11 * M1);
    unsigned short* KL    = (unsigned short*)(ws + 12 * M1);
    unsigned short* VT    = (unsigned short*)(ws + 13 * M1);
    // hs pre-split overlays KH/KL/VT (dead until prep_k/prep_v)
    unsigned short* hsH   = (unsigned short*)(ws + 11 * M1);  // [4096][1024]
    unsigned short* hsL   = (unsigned short*)(ws + 13 * M1);
    float* out = (float*)d_out;

    static bool attr_set = false;
    if (!attr_set) {
        hipFuncSetAttribute((const void*)attn,
                            hipFuncAttributeMaxDynamicSharedMemorySize, 70784);
        attr_set = true;
    }

    dim3 blk(256);
    prep_wt_all<<<dim3(16, 48), blk, 0, stream>>>(wq, wk, wv, wo,
                                                  QKVWh, QKVWl, WoH, WoL);
    split_a<<<dim3(4096), blk, 0, stream>>>(hs, hsH, hsL);
    gemm_bf<<<dim3(32, 16), blk, 0, stream>>>(hsH, hsL, 1024, QKVWh, QKVWl,
                                              QKV, 1024, 2048);
    prep_k<<<dim3(8192), blk, 0, stream>>>(QKV, KH, KL, pos);
    prep_v<<<dim3(512),  blk, 0, stream>>>(QKV, VT);
    attn<<<dim3(4096), dim3(512), 70784, stream>>>(QKV, KH, KL, VT, pos,
                                                   (unsigned short*)QKV);
    gemm_bf<<<dim3(32, 8), blk, 0, stream>>>((unsigned short*)QKV + 2048,
                                             (unsigned short*)QKV + 3072, 4096,
                                             WoH, WoL, out, 1024, 1024);
}

// Round 14
// 767.277 us; speedup vs baseline: 1.0436x; 1.0436x over previous
//
#include <hip/hip_runtime.h>
#include <cstdint>
#include <cstddef>

typedef unsigned int u32;
typedef unsigned long long u64;
typedef __attribute__((ext_vector_type(8))) short s8v;   // 8 bf16 (4 VGPRs)
typedef __attribute__((ext_vector_type(4))) float f4v;   // MFMA C/D
typedef __attribute__((ext_vector_type(4))) unsigned short us4;

#define B_   2
#define L_   2048
#define D_   1024
#define NH_  16
#define KVH_ 8
#define DH_  64
#define TOPK_ 1024

#define MFMA16(a, b, c) __builtin_amdgcn_mfma_f32_16x16x32_bf16(a, b, c, 0, 0, 0)

// order-preserving float->uint key (descending float == descending uint)
__device__ __forceinline__ u32 fkey(float s) {
    u32 b = __float_as_uint(s);
    return b ^ ((u32)((int)b >> 31) | 0x80000000u);
}
// exact inverse of fkey
__device__ __forceinline__ float fkeyinv(u32 k) {
    u32 b = (k & 0x80000000u) ? (k ^ 0x80000000u) : ~k;
    return __uint_as_float(b);
}
// fp32 -> bf16 round-to-nearest-even, as raw ushort
__device__ __forceinline__ unsigned short bf16rne(float x) {
    u32 u = __float_as_uint(x);
    u32 r = (u + 0x7FFFu + ((u >> 16) & 1u)) >> 16;
    return (unsigned short)r;
}
__device__ __forceinline__ float bf2f(unsigned short h) {
    return __uint_as_float((u32)h << 16);
}

// ---------------------------------------------------------------------------
// All weight preps in ONE launch. grid (16, 48): by<16 wq -> QKVW rows 0..1023,
// 16..23 wk -> rows 1024..1535, 24..31 wv -> rows 1536..2047, 32..47 wo -> Wo.
// W [K=1024][N] fp32 -> dest [row][1024] bf16 hi/lo (transpose + split).
// ---------------------------------------------------------------------------
__global__ __launch_bounds__(256) void prep_wt_all(
    const float* __restrict__ wq, const float* __restrict__ wk,
    const float* __restrict__ wv, const float* __restrict__ wo,
    unsigned short* __restrict__ QKVWh, unsigned short* __restrict__ QKVWl,
    unsigned short* __restrict__ WoH, unsigned short* __restrict__ WoL) {
    __shared__ float tile[64 * 65];
    const int k0 = blockIdx.x * 64;
    const int byy = blockIdx.y;
    const float* W;
    unsigned short *Dh, *Dl;
    int N, n0, nrow;
    if (byy < 16)      { W = wq; N = 1024; n0 = byy * 64;        Dh = QKVWh; Dl = QKVWl; nrow = byy * 64; }
    else if (byy < 24) { W = wk; N = 512;  n0 = (byy - 16) * 64; Dh = QKVWh; Dl = QKVWl; nrow = 1024 + (byy - 16) * 64; }
    else if (byy < 32) { W = wv; N = 512;  n0 = (byy - 24) * 64; Dh = QKVWh; Dl = QKVWl; nrow = 1536 + (byy - 24) * 64; }
    else               { W = wo; N = 1024; n0 = (byy - 32) * 64; Dh = WoH;   Dl = WoL;   nrow = (byy - 32) * 64; }
    int t = threadIdx.x;
#pragma unroll
    for (int i = 0; i < 16; ++i) {
        int idx = t + i * 256;
        int kk = idx >> 6, nn = idx & 63;
        tile[kk * 65 + nn] = W[(size_t)(k0 + kk) * N + n0 + nn];
    }
    __syncthreads();
#pragma unroll
    for (int i = 0; i < 16; ++i) {
        int idx = t + i * 256;
        int nn = idx >> 6, kk = idx & 63;
        float x = tile[kk * 65 + nn];
        unsigned short hi = bf16rne(x);
        unsigned short lo = bf16rne(x - bf2f(hi));
        Dh[(size_t)(nrow + nn) * 1024 + k0 + kk] = hi;
        Dl[(size_t)(nrow + nn) * 1024 + k0 + kk] = lo;
    }
}

// ---------------------------------------------------------------------------
// A [M][K] fp32 -> AH/AL bf16 hi/lo (same layout). 4 elems/thread.
// ---------------------------------------------------------------------------
__global__ __launch_bounds__(256) void split_a(const float* __restrict__ A,
                                               unsigned short* __restrict__ AH,
                                               unsigned short* __restrict__ AL) {
    size_t tid = (size_t)blockIdx.x * 256 + threadIdx.x;
    float4 v = *(const float4*)(A + tid * 4);
    us4 hv, lv;
    float x[4] = {v.x, v.y, v.z, v.w};
#pragma unroll
    for (int i = 0; i < 4; ++i) {
        unsigned short hi = bf16rne(x[i]);
        hv[i] = hi;
        lv[i] = bf16rne(x[i] - bf2f(hi));
    }
    *(us4*)(AH + tid * 4) = hv;
    *(us4*)(AL + tid * 4) = lv;
}

// ---------------------------------------------------------------------------
// MFMA GEMM, bf16-A variant: C[M][N] fp32 = A(hi/lo bf16, row stride lda)
// @ Wt([N][K] bf16 hi/lo), 3-term hi/lo. BM=BN=128, BK=32; 256 thr.
// grid (M/128, N/128), XCD-chunked swizzle (nwg%8==0).
// ---------------------------------------------------------------------------
__global__ __launch_bounds__(256) void gemm_bf(
    const unsigned short* __restrict__ Ah,
    const unsigned short* __restrict__ Al,
    int lda,
    const unsigned short* __restrict__ Wh,
    const unsigned short* __restrict__ Wl,
    float* __restrict__ C, int K, int N) {
    __shared__ __align__(16) unsigned short lAh[128 * 40];
    __shared__ __align__(16) unsigned short lAl[128 * 40];
    __shared__ __align__(16) unsigned short lBh[128 * 40];
    __shared__ __align__(16) unsigned short lBl[128 * 40];
    const int t = threadIdx.x, lane = t & 63, w = t >> 6;
    const int quad = lane >> 4, col = lane & 15;
    const int wm = w >> 1, wn = w & 1;
    const int nwg = gridDim.x * gridDim.y;
    const int lin = blockIdx.y * gridDim.x + blockIdx.x;
    const int swz = (lin & 7) * (nwg >> 3) + (lin >> 3);
    const int bx = swz % gridDim.x, by = swz / gridDim.x;
    const int m0 = bx * 128, n0 = by * 128;
    const int sr = t >> 1, sk = (t & 1) * 16;

    f4v acc[4][4];
#pragma unroll
    for (int i = 0; i < 4; ++i)
#pragma unroll
        for (int j = 0; j < 4; ++j) acc[i][j] = (f4v){0.f, 0.f, 0.f, 0.f};

    for (int k0 = 0; k0 < K; k0 += 32) {
        const unsigned short* ap = Ah + (size_t)(m0 + sr) * lda + k0 + sk;
        const unsigned short* alp = Al + (size_t)(m0 + sr) * lda + k0 + sk;
        s8v a_h0 = *(const s8v*)(ap);
        s8v a_h1 = *(const s8v*)(ap + 8);
        s8v a_l0 = *(const s8v*)(alp);
        s8v a_l1 = *(const s8v*)(alp + 8);
        s8v bh0 = *(const s8v*)(Wh + (size_t)(n0 + sr) * K + k0 + sk);
        s8v bh1 = *(const s8v*)(Wh + (size_t)(n0 + sr) * K + k0 + sk + 8);
        s8v bl0 = *(const s8v*)(Wl + (size_t)(n0 + sr) * K + k0 + sk);
        s8v bl1 = *(const s8v*)(Wl + (size_t)(n0 + sr) * K + k0 + sk + 8);
        __syncthreads();
        *(s8v*)&lAh[sr * 40 + sk]     = a_h0;
        *(s8v*)&lAh[sr * 40 + sk + 8] = a_h1;
        *(s8v*)&lAl[sr * 40 + sk]     = a_l0;
        *(s8v*)&lAl[sr * 40 + sk + 8] = a_l1;
        *(s8v*)&lBh[sr * 40 + sk]     = bh0;
        *(s8v*)&lBh[sr * 40 + sk + 8] = bh1;
        *(s8v*)&lBl[sr * 40 + sk]     = bl0;
        *(s8v*)&lBl[sr * 40 + sk + 8] = bl1;
        __syncthreads();
        s8v amh[4], aml[4], bnh[4], bnl[4];
#pragma unroll
        for (int mt = 0; mt < 4; ++mt) {
            amh[mt] = *(s8v*)&lAh[(wm * 64 + mt * 16 + col) * 40 + quad * 8];
            aml[mt] = *(s8v*)&lAl[(wm * 64 + mt * 16 + col) * 40 + quad * 8];
        }
#pragma unroll
        for (int nt = 0; nt < 4; ++nt) {
            bnh[nt] = *(s8v*)&lBh[(wn * 64 + nt * 16 + col) * 40 + quad * 8];
            bnl[nt] = *(s8v*)&lBl[(wn * 64 + nt * 16 + col) * 40 + quad * 8];
        }
#pragma unroll
        for (int mt = 0; mt < 4; ++mt)
#pragma unroll
            for (int nt = 0; nt < 4; ++nt) {
                acc[mt][nt] = MFMA16(amh[mt], bnh[nt], acc[mt][nt]);
                acc[mt][nt] = MFMA16(amh[mt], bnl[nt], acc[mt][nt]);
                acc[mt][nt] = MFMA16(aml[mt], bnh[nt], acc[mt][nt]);
            }
    }
#pragma unroll
    for (int mt = 0; mt < 4; ++mt)
#pragma unroll
        for (int nt = 0; nt < 4; ++nt)
#pragma unroll
            for (int r = 0; r < 4; ++r)
                C[(size_t)(m0 + wm * 64 + mt * 16 + quad * 4 + r) * N +
                  n0 + wn * 64 + nt * 16 + col] = acc[mt][nt][r];
}

// ---------------------------------------------------------------------------
// RoPE on Q, in place. Q in fused QKV buffer: row stride 2048, cols 0..1023.
// ---------------------------------------------------------------------------
__global__ __launch_bounds__(256) void rope_q(float* __restrict__ Q,
                                              const int* __restrict__ pos) {
    int tid = blockIdx.x * 256 + threadIdx.x;
    int dl = tid & 31;
    int h  = (tid >> 5) & 15;
    int l  = (tid >> 9) & 2047;
    int b  = tid >> 20;
    size_t base = (size_t)(b * L_ + l) * 2048 + h * DH_;
    float x1 = Q[base + dl];
    float x2 = Q[base + dl + 32];
    float p = (float)pos[b * L_ + l];
    float invf = (float)pow(10000.0, -(double)dl / 32.0);
    float a = p * invf;
    float s, c;
    sincosf(a, &s, &c);
    Q[base + dl]      = x1 * c - x2 * s;
    Q[base + dl + 32] = x2 * c + x1 * s;
}

// ---------------------------------------------------------------------------
// RoPE on K + hi/lo bf16 split. K in fused QKV: row stride 2048, col
// 1024 + kvh*64 + d. Output layout [b][kvh][l][d].
// ---------------------------------------------------------------------------
__global__ __launch_bounds__(256) void prep_k(const float* __restrict__ QKV,
                                              unsigned short* __restrict__ KHp,
                                              unsigned short* __restrict__ KLp,
                                              const int* __restrict__ pos) {
    int tid = blockIdx.x * 256 + threadIdx.x;
    int d   = tid & 63;
    int l   = (tid >> 6) & 2047;
    int kvh = (tid >> 17) & 7;
    int b   = tid >> 20;
    size_t src = (size_t)(b * L_ + l) * 2048 + 1024 + kvh * DH_;
    float x  = QKV[src + d];
    int dp   = (d < 32) ? d + 32 : d - 32;
    float xp = QKV[src + dp];
    float p = (float)pos[b * L_ + l];
    int i = d & 31;
    float invf = (float)pow(10000.0, -(double)i / 32.0);
    float a = p * invf;
    float s, c;
    sincosf(a, &s, &c);
    float out = (d < 32) ? (x * c - xp * s) : (x * c + xp * s);
    unsigned short hi = bf16rne(out);
    unsigned short lo = bf16rne(out - bf2f(hi));
    size_t dst = ((size_t)(b * KVH_ + kvh) * L_ + l) * DH_ + d;
    KHp[dst] = hi;
    KLp[dst] = lo;
}

// ---------------------------------------------------------------------------
// V transpose to bf16 from fused QKV (V at col 1536 + kvh*64 + d, stride 2048)
// -> VT[b][kvh][d][l]
// ---------------------------------------------------------------------------
__global__ __launch_bounds__(256) void prep_v(const float* __restrict__ QKV,
                                              unsigned short* __restrict__ VTp) {
    __shared__ float tile[64 * 65];
    int bid = blockIdx.x;
    int lb  = bid & 31;
    int kvh = (bid >> 5) & 7;
    int b   = bid >> 8;
    int l0  = lb * 64;
    int t   = threadIdx.x;
#pragma unroll
    for (int i = 0; i < 16; ++i) {
        int idx = t + i * 256;
        int ll = idx >> 6, d = idx & 63;
        tile[ll * 65 + d] =
            QKV[(size_t)(b * L_ + l0 + ll) * 2048 + 1536 + kvh * DH_ + d];
    }
    __syncthreads();
#pragma unroll
    for (int i = 0; i < 16; ++i) {
        int idx = t + i * 256;
        int d = idx >> 6, ll = idx & 63;
        VTp[((size_t)(b * KVH_ + kvh) * DH_ + d) * L_ + l0 + ll] = bf16rne(tile[ll * 65 + d]);
    }
}

// ---------------------------------------------------------------------------
// Fused sparse attention, R22 = R20 verbatim (best measured: attn 604us).
// R21 post-mortem: intra-wave interleaving of the two middles regressed
// (-26us) -- the two sequential middles were ALREADY overlapped across the
// two resident blocks (R18 mechanism); duplicating concurrency intra-wave
// cost VALU/branch/state for nothing. Fused RoPE also added serial
// pow/sincos to the critical kernel. Reverted both; kept prep_wt_all.
// Structure: 8 waves / 16 q-rows (2 per wave), 2 blocks/CU (2 barrier
// domains), sequential dual middles sharing one 4x-replicated
// time-multiplexed hist (Sc U Pc U hist, live ranges disjoint).
// ---------------------------------------------------------------------------
__global__ __launch_bounds__(512, 4) void attn(
    const float* __restrict__ QR,
    const unsigned short* __restrict__ KH,
    const unsigned short* __restrict__ KL,
    const unsigned short* __restrict__ VT,
    unsigned short* __restrict__ AOus) {

    extern __shared__ __align__(16) unsigned char dynsm[];
    float* Sc = (float*)dynsm;                     // [16][1034] f32 = 66176B
    unsigned short* Pc = (unsigned short*)dynsm;   // [16][2072] us = 66304B (union)
    u32* hist = (u32*)dynsm;                       // [8][1024] u32 = 32768B (union;
                                                   // live only between Sc-reads-done
                                                   // and the pre-Pc barrier)
    float* qtile  = (float*)(dynsm + 66304);       // [16][68] f32 = 4352B
    float* outred = (float*)(dynsm + 66304);       // union w/ qtile (dead after A-frags)

    const int t = threadIdx.x;                     // 0..511
    const int lane = t & 63, w = t >> 6;           // w in [0,8)
    const int quad = lane >> 4, col = lane & 15;
    // XCD-chunked remap (bijective: 4096 % 8 == 0)
    const int bid0 = blockIdx.x;
    const int bid  = (bid0 & 7) * 512 + (bid0 >> 3);
    const int l0  = (bid & 255) * 8;
    const int kvh = (bid >> 8) & 7;
    const int b   = bid >> 11;
    const int r0 = 2 * w, r1 = 2 * w + 1;          // q-rows owned by this wave

    // ---- load Q tile (16 rows = 8 l-pos x heads {2kvh, 2kvh+1})
    if (t < 256) {
        int q = t >> 4, d4 = (t & 15) * 4;
        *(float4*)&qtile[q * 68 + d4] =
            *(const float4*)(QR + (size_t)(b * L_ + l0 + (q & 7)) * 2048 +
                             (kvh * 2 + (q >> 3)) * DH_ + d4);
    }
    __syncthreads();

    // ---- build A-frags (hi/lo): A[m=col][k=ks*32+quad*8+i]; all 16 rows real
    union FR { s8v v; unsigned short u[8]; };
    FR ah[2], al[2];
#pragma unroll
    for (int ks = 0; ks < 2; ++ks)
#pragma unroll
        for (int i = 0; i < 8; ++i) {
            float x = qtile[col * 68 + ks * 32 + quad * 8 + i];
            unsigned short hi = bf16rne(x);
            ah[ks].u[i] = hi;
            al[ks].u[i] = bf16rne(x - bf2f(hi));
        }

    // ---- QK^T in 2 J-halves of 1024 cols (wave slice 128 cols = 8 tj/half)
    const size_t slabK = (size_t)(b * KVH_ + kvh) * L_ * DH_;
    const unsigned short* khp = KH + slabK;
    const unsigned short* klp = KL + slabK;
    u32 ukA[32], ukB[32];   // keys: elem i <-> j = 1024*(i>>4) + 64*(i&15) + lane

#pragma unroll
    for (int half = 0; half < 2; ++half) {
        if (half) __syncthreads();       // half0 reads done before rewrite
#pragma unroll
        for (int tj = 0; tj < 8; ++tj) {
            int jl = w * 128 + tj * 16;  // col within half
            int j0 = half * 1024 + jl;   // global col
            const unsigned short* kh8 = khp + (size_t)(j0 + col) * 64 + quad * 8;
            const unsigned short* kl8 = klp + (size_t)(j0 + col) * 64 + quad * 8;
            s8v bh0 = *(const s8v*)(kh8);
            s8v bh1 = *(const s8v*)(kh8 + 32);
            s8v bl0 = *(const s8v*)(kl8);
            s8v bl1 = *(const s8v*)(kl8 + 32);
            f4v c = {0.f, 0.f, 0.f, 0.f};
            c = MFMA16(ah[0].v, bh0, c);
            c = MFMA16(al[0].v, bh0, c);
            c = MFMA16(ah[0].v, bl0, c);
            c = MFMA16(ah[1].v, bh1, c);
            c = MFMA16(al[1].v, bh1, c);
            c = MFMA16(ah[1].v, bl1, c);
            c = c * 0.125f;              // DH^-0.5
#pragma unroll
            for (int r = 0; r < 4; ++r)
                Sc[(quad * 4 + r) * 1034 + jl + col] = c[r];
        }
        __syncthreads();                 // Sc(half) complete
        if (half == 0) {                 // qtile dead; zero outred (union)
            outred[t] = 0.f;
            outred[t + 512] = 0.f;
            if (t < 64) outred[1024 + t] = 0.f;
        }
#pragma unroll
        for (int i2 = 0; i2 < 16; ++i2) {
            ukA[half * 16 + i2] = fkey(Sc[r0 * 1034 + i2 * 64 + lane]);
            ukB[half * 16 + i2] = fkey(Sc[r1 * 1034 + i2 * 64 + lane]);
        }
    }
    __syncthreads();                     // all Sc reads done; region free (hist)

    // ---- wave-local middle (norm + radix top-1024 + softmax), per row.
    // 4x-replicated hist: digit d, replica lane&3 at
    // hq[(d&3)*256 + (d>>2)*4 + (lane&3)]; read = bank-optimal uint4.
    u32* hq = &hist[w * 1024];
    const int rep = lane & 3;
    auto middle = [&](u32 (&uk)[32]) -> float {
        // order-preserving normalization
        u32 ulo = 0xFFFFFFFFu, uhi = 0u;
#pragma unroll
        for (int i = 0; i < 32; ++i) {
            u32 u = uk[i];
            ulo = (u < ulo) ? u : ulo;
            uhi = (u > uhi) ? u : uhi;
        }
        for (int off = 1; off < 64; off <<= 1) {
            u32 ol = (u32)__shfl_xor((int)ulo, off);
            u32 oh = (u32)__shfl_xor((int)uhi, off);
            ulo = (ol < ulo) ? ol : ulo;
            uhi = (oh > uhi) ? oh : uhi;
        }
        const float mrow = fkeyinv(uhi);
        const int sh = __clz((int)((uhi - ulo) | 1u));
#pragma unroll
        for (int i = 0; i < 32; ++i) uk[i] = (uk[i] - ulo) << sh;

        // radix with wave-uniform early-exit
        u32 pf = 0u, kq = (u32)TOPK_, ng = 0u, geq = 0u;
        for (int pass = 0; pass < 4; ++pass) {
            int shift = 24 - 8 * pass;
#pragma unroll
            for (int i = 0; i < 4; ++i)
                *(uint4*)&hq[i * 256 + lane * 4] = make_uint4(0u, 0u, 0u, 0u);
            u32 pm = pass ? (0xFFFFFFFFu << (shift + 8)) : 0u;
#pragma unroll
            for (int i = 0; i < 32; ++i) {
                u32 u = uk[i];
                if ((u & pm) == pf) {
                    u32 d = (u >> shift) & 255u;
                    atomicAdd(&hq[(d & 3) * 256 + (d >> 2) * 4 + rep], 1u);
                }
            }
            u32 hb_[4];
            u32 s4 = 0u;
#pragma unroll
            for (int bb = 0; bb < 4; ++bb) {
                uint4 hv = *(const uint4*)&hq[bb * 256 + lane * 4];
                hb_[bb] = hv.x + hv.y + hv.z + hv.w;
                s4 += hb_[bb];
            }
            u32 v = s4;
            for (int off = 1; off < 64; off <<= 1) {
                u32 tmp = __shfl_down(v, off);
                if (lane + off < 64) v += tmp;
            }
            u32 g = v - s4;
            u32 mydig = 0u, myk = 0u, myng = 0u, myhb = 0u;
            bool found = false;
#pragma unroll
            for (int bb = 3; bb >= 0; --bb) {
                u32 hb = hb_[bb];
                if (hb && g < kq && kq <= g + hb) {
                    found = true;
                    mydig = (u32)(4 * lane + bb);
                    myk   = kq - g;
                    myng  = ng + g;
                    myhb  = hb;
                }
                g += hb;
            }
            u64 fm = __ballot(found);
            int src = (int)__builtin_ctzll(fm);
            pf |= ((u32)__shfl((int)mydig, src)) << shift;
            kq  = (u32)__shfl((int)myk,  src);
            ng  = (u32)__shfl((int)myng, src);
            u32 hbs = (u32)__shfl((int)myhb, src);
            if (kq == hbs) { geq = 1u; break; }
        }

        // selection mask
        const u32 uth = pf;
        u32 selm = 0u;
        if (geq) {
#pragma unroll
            for (int i = 0; i < 32; ++i)
                if (uk[i] >= uth) selm |= 1u << i;
        } else {
            const u32 quota = (u32)TOPK_ - ng;
            u32 eqm = 0u;
#pragma unroll
            for (int i = 0; i < 32; ++i) {
                u32 u = uk[i];
                if (u > uth) selm |= 1u << i;
                else if (u == uth) eqm |= 1u << i;
            }
            u32 ec = (u32)__builtin_popcount(eqm);
            for (int off = 1; off < 64; off <<= 1) ec += __shfl_xor(ec, off);
            if (ec == quota) {
                selm |= eqm;
            } else {
                u32 base = 0;
                u64 lmask = ((u64)1 << lane) - 1;
#pragma unroll
                for (int i = 0; i < 32; ++i) {
                    u64 mm = __ballot((eqm >> i) & 1u);
                    if ((eqm >> i) & 1u) {
                        u32 rk = base + (u32)__builtin_popcountll(mm & lmask);
                        if (rk < quota) selm |= 1u << i;
                    }
                    base += (u32)__builtin_popcountll(mm);
                }
            }
        }

        // softmax: e into uk, return invZ
        float z = 0.f;
#pragma unroll
        for (int i = 0; i < 32; ++i) {
            float vv = fkeyinv((uk[i] >> sh) + ulo);      // exact inverse
            float e = ((selm >> i) & 1u) ? __expf(vv - mrow) : 0.f;
            uk[i] = __float_as_uint(e);
            z += e;
        }
        for (int off = 1; off < 64; off <<= 1) z += __shfl_xor(z, off);
        return 1.0f / z;
    };

    float invZA = middle(ukA);
    float invZB = middle(ukB);

    // ---- prefetch kc0 V tiles (L2 loads overlap the barrier + P writes)
    const unsigned short* vt = VT + (size_t)(b * KVH_ + kvh) * DH_ * L_;
    const int jb0 = w * 256 + quad * 8;
    s8v pv0 = *(const s8v*)(vt + (size_t)( 0 + col) * L_ + jb0);
    s8v pv1 = *(const s8v*)(vt + (size_t)(16 + col) * L_ + jb0);
    s8v pv2 = *(const s8v*)(vt + (size_t)(32 + col) * L_ + jb0);
    s8v pv3 = *(const s8v*)(vt + (size_t)(48 + col) * L_ + jb0);

    __syncthreads();                     // all hist use done; Pc region free

    // ---- P -> Pc (bf16, invZ folded); rows r0, r1. Pc[row][j], j packed
    // identically to uk element mapping.
#pragma unroll
    for (int i = 0; i < 32; ++i) {
        int jp = 1024 * (i >> 4) + 64 * (i & 15) + lane;
        Pc[r0 * 2072 + jp] = bf16rne(__uint_as_float(ukA[i]) * invZA);
        Pc[r1 * 2072 + jp] = bf16rne(__uint_as_float(ukB[i]) * invZB);
    }
    __syncthreads();                     // all P rows written

    // ---- PV via MFMA; wave w covers j in [256w, 256w+256) in 8 sub-chunks
    f4v acc0 = {0.f, 0.f, 0.f, 0.f}, acc1 = acc0, acc2 = acc0, acc3 = acc0;
    {
        s8v ap = *(const s8v*)&Pc[col * 2072 + jb0];
        acc0 = MFMA16(ap, pv0, acc0);
        acc1 = MFMA16(ap, pv1, acc1);
        acc2 = MFMA16(ap, pv2, acc2);
        acc3 = MFMA16(ap, pv3, acc3);
    }
#pragma unroll
    for (int kc = 1; kc < 8; ++kc) {
        int jb = w * 256 + kc * 32 + quad * 8;
        s8v ap = *(const s8v*)&Pc[col * 2072 + jb];
        s8v v0 = *(const s8v*)(vt + (size_t)( 0 + col) * L_ + jb);
        s8v v1 = *(const s8v*)(vt + (size_t)(16 + col) * L_ + jb);
        s8v v2 = *(const s8v*)(vt + (size_t)(32 + col) * L_ + jb);
        s8v v3 = *(const s8v*)(vt + (size_t)(48 + col) * L_ + jb);
        acc0 = MFMA16(ap, v0, acc0);
        acc1 = MFMA16(ap, v1, acc1);
        acc2 = MFMA16(ap, v2, acc2);
        acc3 = MFMA16(ap, v3, acc3);
    }

    // ---- cross-wave PV reduction (all 16 rows live) + store as bf16 hi/lo
#pragma unroll
    for (int r = 0; r < 4; ++r) {
        atomicAdd(&outred[(quad * 4 + r) * 68 +  0 + col], acc0[r]);
        atomicAdd(&outred[(quad * 4 + r) * 68 + 16 + col], acc1[r]);
        atomicAdd(&outred[(quad * 4 + r) * 68 + 32 + col], acc2[r]);
        atomicAdd(&outred[(quad * 4 + r) * 68 + 48 + col], acc3[r]);
    }
    __syncthreads();
    if (t < 256) {
        int q = t >> 4, d4 = (t & 15) * 4;
        float4 o = *(float4*)&outred[q * 68 + d4];
        size_t m = (size_t)(b * L_ + l0 + (q & 7));
        int n = (kvh * 2 + (q >> 3)) * DH_ + d4;
        float x[4] = {o.x, o.y, o.z, o.w};
        us4 hv, lv;
#pragma unroll
        for (int i = 0; i < 4; ++i) {
            unsigned short hi = bf16rne(x[i]);
            hv[i] = hi;
            lv[i] = bf16rne(x[i] - bf2f(hi));
        }
        *(us4*)(AOus + m * 4096 + 2048 + n) = hv;
        *(us4*)(AOus + m * 4096 + 3072 + n) = lv;
    }
}

// ---------------------------------------------------------------------------
extern "C" void kernel_launch(void* const* d_in, const int* in_sizes, int n_in,
                              void* d_out, int out_size, void* d_ws, size_t ws_size,
                              hipStream_t stream) {
    const float* hs = (const float*)d_in[0];
    const float* wq = (const float*)d_in[1];
    const float* wk = (const float*)d_in[2];
    const float* wv = (const float*)d_in[3];
    const float* wo = (const float*)d_in[4];
    const int*  pos = (const int*)d_in[5];

    float* ws = (float*)d_ws;
    const size_t M1 = 1u << 20;
    float* QKV = ws;                           // [0, 8M) fp32 [4096][2048]
    unsigned short* QKVWh = (unsigned short*)(ws +  8 * M1);  // [2048][1024]
    unsigned short* QKVWl = (unsigned short*)(ws +  9 * M1);
    unsigned short* WoH   = (unsigned short*)(ws + 10 * M1);
    unsigned short* WoL   = (unsigned short*)(ws + 10 * M1 + M1 / 2);
    unsigned short* KH    = (unsigned short*)(ws + 11 * M1);
    unsigned short* KL    = (unsigned short*)(ws + 12 * M1);
    unsigned short* VT    = (unsigned short*)(ws + 13 * M1);
    // hs pre-split overlays KH/KL/VT (dead until prep_k/prep_v)
    unsigned short* hsH   = (unsigned short*)(ws + 11 * M1);  // [4096][1024]
    unsigned short* hsL   = (unsigned short*)(ws + 13 * M1);
    float* out = (float*)d_out;

    static bool attr_set = false;
    if (!attr_set) {
        hipFuncSetAttribute((const void*)attn,
                            hipFuncAttributeMaxDynamicSharedMemorySize, 70656);
        attr_set = true;
    }

    dim3 blk(256);
    prep_wt_all<<<dim3(16, 48), blk, 0, stream>>>(wq, wk, wv, wo,
                                                  QKVWh, QKVWl, WoH, WoL);
    split_a<<<dim3(4096), blk, 0, stream>>>(hs, hsH, hsL);
    gemm_bf<<<dim3(32, 16), blk, 0, stream>>>(hsH, hsL, 1024, QKVWh, QKVWl,
                                              QKV, 1024, 2048);
    rope_q<<<dim3(8192), blk, 0, stream>>>(QKV, pos);
    prep_k<<<dim3(8192), blk, 0, stream>>>(QKV, KH, KL, pos);
    prep_v<<<dim3(512),  blk, 0, stream>>>(QKV, VT);
    attn<<<dim3(4096), dim3(512), 70656, stream>>>(QKV, KH, KL, VT,
                                                   (unsigned short*)QKV);
    gemm_bf<<<dim3(32, 8), blk, 0, stream>>>((unsigned short*)QKV + 2048,
                                             (unsigned short*)QKV + 3072, 4096,
                                             WoH, WoL, out, 1024, 1024);
}

// Round 15
// 755.631 us; speedup vs baseline: 1.0597x; 1.0154x over previous
//
#include <hip/hip_runtime.h>
#include <cstdint>
#include <cstddef>

typedef unsigned int u32;
typedef unsigned long long u64;
typedef __attribute__((ext_vector_type(8))) short s8v;   // 8 bf16 (4 VGPRs)
typedef __attribute__((ext_vector_type(4))) float f4v;   // MFMA C/D
typedef __attribute__((ext_vector_type(4))) unsigned short us4;

#define B_   2
#define L_   2048
#define D_   1024
#define NH_  16
#define KVH_ 8
#define DH_  64
#define TOPK_ 1024

#define MFMA16(a, b, c) __builtin_amdgcn_mfma_f32_16x16x32_bf16(a, b, c, 0, 0, 0)

// order-preserving float->uint key (descending float == descending uint)
__device__ __forceinline__ u32 fkey(float s) {
    u32 b = __float_as_uint(s);
    return b ^ ((u32)((int)b >> 31) | 0x80000000u);
}
// exact inverse of fkey
__device__ __forceinline__ float fkeyinv(u32 k) {
    u32 b = (k & 0x80000000u) ? (k ^ 0x80000000u) : ~k;
    return __uint_as_float(b);
}
// fp32 -> bf16 round-to-nearest-even, as raw ushort
__device__ __forceinline__ unsigned short bf16rne(float x) {
    u32 u = __float_as_uint(x);
    u32 r = (u + 0x7FFFu + ((u >> 16) & 1u)) >> 16;
    return (unsigned short)r;
}
__device__ __forceinline__ float bf2f(unsigned short h) {
    return __uint_as_float((u32)h << 16);
}

// ---------------------------------------------------------------------------
// All weight preps in ONE launch. grid (16, 48): by<16 wq -> QKVW rows 0..1023,
// 16..23 wk -> rows 1024..1535, 24..31 wv -> rows 1536..2047, 32..47 wo -> Wo.
// ---------------------------------------------------------------------------
__global__ __launch_bounds__(256) void prep_wt_all(
    const float* __restrict__ wq, const float* __restrict__ wk,
    const float* __restrict__ wv, const float* __restrict__ wo,
    unsigned short* __restrict__ QKVWh, unsigned short* __restrict__ QKVWl,
    unsigned short* __restrict__ WoH, unsigned short* __restrict__ WoL) {
    __shared__ float tile[64 * 65];
    const int k0 = blockIdx.x * 64;
    const int byy = blockIdx.y;
    const float* W;
    unsigned short *Dh, *Dl;
    int N, n0, nrow;
    if (byy < 16)      { W = wq; N = 1024; n0 = byy * 64;        Dh = QKVWh; Dl = QKVWl; nrow = byy * 64; }
    else if (byy < 24) { W = wk; N = 512;  n0 = (byy - 16) * 64; Dh = QKVWh; Dl = QKVWl; nrow = 1024 + (byy - 16) * 64; }
    else if (byy < 32) { W = wv; N = 512;  n0 = (byy - 24) * 64; Dh = QKVWh; Dl = QKVWl; nrow = 1536 + (byy - 24) * 64; }
    else               { W = wo; N = 1024; n0 = (byy - 32) * 64; Dh = WoH;   Dl = WoL;   nrow = (byy - 32) * 64; }
    int t = threadIdx.x;
#pragma unroll
    for (int i = 0; i < 16; ++i) {
        int idx = t + i * 256;
        int kk = idx >> 6, nn = idx & 63;
        tile[kk * 65 + nn] = W[(size_t)(k0 + kk) * N + n0 + nn];
    }
    __syncthreads();
#pragma unroll
    for (int i = 0; i < 16; ++i) {
        int idx = t + i * 256;
        int nn = idx >> 6, kk = idx & 63;
        float x = tile[kk * 65 + nn];
        unsigned short hi = bf16rne(x);
        unsigned short lo = bf16rne(x - bf2f(hi));
        Dh[(size_t)(nrow + nn) * 1024 + k0 + kk] = hi;
        Dl[(size_t)(nrow + nn) * 1024 + k0 + kk] = lo;
    }
}

// ---------------------------------------------------------------------------
// A [M][K] fp32 -> AH/AL bf16 hi/lo (same layout). 4 elems/thread.
// ---------------------------------------------------------------------------
__global__ __launch_bounds__(256) void split_a(const float* __restrict__ A,
                                               unsigned short* __restrict__ AH,
                                               unsigned short* __restrict__ AL) {
    size_t tid = (size_t)blockIdx.x * 256 + threadIdx.x;
    float4 v = *(const float4*)(A + tid * 4);
    us4 hv, lv;
    float x[4] = {v.x, v.y, v.z, v.w};
#pragma unroll
    for (int i = 0; i < 4; ++i) {
        unsigned short hi = bf16rne(x[i]);
        hv[i] = hi;
        lv[i] = bf16rne(x[i] - bf2f(hi));
    }
    *(us4*)(AH + tid * 4) = hv;
    *(us4*)(AL + tid * 4) = lv;
}

// ---------------------------------------------------------------------------
// MFMA GEMM, bf16-A variant: C[M][N] fp32 = A(hi/lo bf16, row stride lda)
// @ Wt([N][K] bf16 hi/lo), 3-term hi/lo. BM=BN=128, BK=32; 256 thr.
// grid (M/128, N/128), XCD-chunked swizzle (nwg%8==0).
// ---------------------------------------------------------------------------
__global__ __launch_bounds__(256) void gemm_bf(
    const unsigned short* __restrict__ Ah,
    const unsigned short* __restrict__ Al,
    int lda,
    const unsigned short* __restrict__ Wh,
    const unsigned short* __restrict__ Wl,
    float* __restrict__ C, int K, int N) {
    __shared__ __align__(16) unsigned short lAh[128 * 40];
    __shared__ __align__(16) unsigned short lAl[128 * 40];
    __shared__ __align__(16) unsigned short lBh[128 * 40];
    __shared__ __align__(16) unsigned short lBl[128 * 40];
    const int t = threadIdx.x, lane = t & 63, w = t >> 6;
    const int quad = lane >> 4, col = lane & 15;
    const int wm = w >> 1, wn = w & 1;
    const int nwg = gridDim.x * gridDim.y;
    const int lin = blockIdx.y * gridDim.x + blockIdx.x;
    const int swz = (lin & 7) * (nwg >> 3) + (lin >> 3);
    const int bx = swz % gridDim.x, by = swz / gridDim.x;
    const int m0 = bx * 128, n0 = by * 128;
    const int sr = t >> 1, sk = (t & 1) * 16;

    f4v acc[4][4];
#pragma unroll
    for (int i = 0; i < 4; ++i)
#pragma unroll
        for (int j = 0; j < 4; ++j) acc[i][j] = (f4v){0.f, 0.f, 0.f, 0.f};

    for (int k0 = 0; k0 < K; k0 += 32) {
        const unsigned short* ap = Ah + (size_t)(m0 + sr) * lda + k0 + sk;
        const unsigned short* alp = Al + (size_t)(m0 + sr) * lda + k0 + sk;
        s8v a_h0 = *(const s8v*)(ap);
        s8v a_h1 = *(const s8v*)(ap + 8);
        s8v a_l0 = *(const s8v*)(alp);
        s8v a_l1 = *(const s8v*)(alp + 8);
        s8v bh0 = *(const s8v*)(Wh + (size_t)(n0 + sr) * K + k0 + sk);
        s8v bh1 = *(const s8v*)(Wh + (size_t)(n0 + sr) * K + k0 + sk + 8);
        s8v bl0 = *(const s8v*)(Wl + (size_t)(n0 + sr) * K + k0 + sk);
        s8v bl1 = *(const s8v*)(Wl + (size_t)(n0 + sr) * K + k0 + sk + 8);
        __syncthreads();
        *(s8v*)&lAh[sr * 40 + sk]     = a_h0;
        *(s8v*)&lAh[sr * 40 + sk + 8] = a_h1;
        *(s8v*)&lAl[sr * 40 + sk]     = a_l0;
        *(s8v*)&lAl[sr * 40 + sk + 8] = a_l1;
        *(s8v*)&lBh[sr * 40 + sk]     = bh0;
        *(s8v*)&lBh[sr * 40 + sk + 8] = bh1;
        *(s8v*)&lBl[sr * 40 + sk]     = bl0;
        *(s8v*)&lBl[sr * 40 + sk + 8] = bl1;
        __syncthreads();
        s8v amh[4], aml[4], bnh[4], bnl[4];
#pragma unroll
        for (int mt = 0; mt < 4; ++mt) {
            amh[mt] = *(s8v*)&lAh[(wm * 64 + mt * 16 + col) * 40 + quad * 8];
            aml[mt] = *(s8v*)&lAl[(wm * 64 + mt * 16 + col) * 40 + quad * 8];
        }
#pragma unroll
        for (int nt = 0; nt < 4; ++nt) {
            bnh[nt] = *(s8v*)&lBh[(wn * 64 + nt * 16 + col) * 40 + quad * 8];
            bnl[nt] = *(s8v*)&lBl[(wn * 64 + nt * 16 + col) * 40 + quad * 8];
        }
#pragma unroll
        for (int mt = 0; mt < 4; ++mt)
#pragma unroll
            for (int nt = 0; nt < 4; ++nt) {
                acc[mt][nt] = MFMA16(amh[mt], bnh[nt], acc[mt][nt]);
                acc[mt][nt] = MFMA16(amh[mt], bnl[nt], acc[mt][nt]);
                acc[mt][nt] = MFMA16(aml[mt], bnh[nt], acc[mt][nt]);
            }
    }
#pragma unroll
    for (int mt = 0; mt < 4; ++mt)
#pragma unroll
        for (int nt = 0; nt < 4; ++nt)
#pragma unroll
            for (int r = 0; r < 4; ++r)
                C[(size_t)(m0 + wm * 64 + mt * 16 + quad * 4 + r) * N +
                  n0 + wn * 64 + nt * 16 + col] = acc[mt][nt][r];
}

// ---------------------------------------------------------------------------
// R23: fused QKV projection GEMM. Same 3-term hi/lo main loop; epilogue
// applies the per-element transforms the old rope_q/prep_k/prep_v kernels
// did by RE-READING the fp32 C from memory -- but the rope pair (d, d+32)
// lives in acc[mt][nt]/acc[mt][nt+2] of the SAME thread (head = 64 cols =
// 4 nt-groups; pairing nt<->nt+2), so all three are register-local:
//   Q cols (hb<1024):   rope -> fp32 Qrope [row][1024]
//   K cols (1024..1535): rope + hi/lo split -> KH/KL [b][kvh][l][64]
//   V cols (1536..2047): bf16 -> VT [b][kvh][d][L] (4 consecutive l = 8B)
// Bit-identical to the separate kernels (same fp32 inputs, same formulas).
// ---------------------------------------------------------------------------
__global__ __launch_bounds__(256) void gemm_qkv(
    const unsigned short* __restrict__ Ah,
    const unsigned short* __restrict__ Al,
    const unsigned short* __restrict__ Wh,
    const unsigned short* __restrict__ Wl,
    const int* __restrict__ pos,
    float* __restrict__ Qrope,
    unsigned short* __restrict__ KHp,
    unsigned short* __restrict__ KLp,
    unsigned short* __restrict__ VTp) {
    const int K = 1024, lda = 1024;
    __shared__ __align__(16) unsigned short lAh[128 * 40];
    __shared__ __align__(16) unsigned short lAl[128 * 40];
    __shared__ __align__(16) unsigned short lBh[128 * 40];
    __shared__ __align__(16) unsigned short lBl[128 * 40];
    const int t = threadIdx.x, lane = t & 63, w = t >> 6;
    const int quad = lane >> 4, col = lane & 15;
    const int wm = w >> 1, wn = w & 1;
    const int nwg = gridDim.x * gridDim.y;   // 512, %8==0
    const int lin = blockIdx.y * gridDim.x + blockIdx.x;
    const int swz = (lin & 7) * (nwg >> 3) + (lin >> 3);
    const int bx = swz % gridDim.x, by = swz / gridDim.x;
    const int m0 = bx * 128, n0 = by * 128;
    const int sr = t >> 1, sk = (t & 1) * 16;

    f4v acc[4][4];
#pragma unroll
    for (int i = 0; i < 4; ++i)
#pragma unroll
        for (int j = 0; j < 4; ++j) acc[i][j] = (f4v){0.f, 0.f, 0.f, 0.f};

    for (int k0 = 0; k0 < K; k0 += 32) {
        const unsigned short* ap = Ah + (size_t)(m0 + sr) * lda + k0 + sk;
        const unsigned short* alp = Al + (size_t)(m0 + sr) * lda + k0 + sk;
        s8v a_h0 = *(const s8v*)(ap);
        s8v a_h1 = *(const s8v*)(ap + 8);
        s8v a_l0 = *(const s8v*)(alp);
        s8v a_l1 = *(const s8v*)(alp + 8);
        s8v bh0 = *(const s8v*)(Wh + (size_t)(n0 + sr) * K + k0 + sk);
        s8v bh1 = *(const s8v*)(Wh + (size_t)(n0 + sr) * K + k0 + sk + 8);
        s8v bl0 = *(const s8v*)(Wl + (size_t)(n0 + sr) * K + k0 + sk);
        s8v bl1 = *(const s8v*)(Wl + (size_t)(n0 + sr) * K + k0 + sk + 8);
        __syncthreads();
        *(s8v*)&lAh[sr * 40 + sk]     = a_h0;
        *(s8v*)&lAh[sr * 40 + sk + 8] = a_h1;
        *(s8v*)&lAl[sr * 40 + sk]     = a_l0;
        *(s8v*)&lAl[sr * 40 + sk + 8] = a_l1;
        *(s8v*)&lBh[sr * 40 + sk]     = bh0;
        *(s8v*)&lBh[sr * 40 + sk + 8] = bh1;
        *(s8v*)&lBl[sr * 40 + sk]     = bl0;
        *(s8v*)&lBl[sr * 40 + sk + 8] = bl1;
        __syncthreads();
        s8v amh[4], aml[4], bnh[4], bnl[4];
#pragma unroll
        for (int mt = 0; mt < 4; ++mt) {
            amh[mt] = *(s8v*)&lAh[(wm * 64 + mt * 16 + col) * 40 + quad * 8];
            aml[mt] = *(s8v*)&lAl[(wm * 64 + mt * 16 + col) * 40 + quad * 8];
        }
#pragma unroll
        for (int nt = 0; nt < 4; ++nt) {
            bnh[nt] = *(s8v*)&lBh[(wn * 64 + nt * 16 + col) * 40 + quad * 8];
            bnl[nt] = *(s8v*)&lBl[(wn * 64 + nt * 16 + col) * 40 + quad * 8];
        }
#pragma unroll
        for (int mt = 0; mt < 4; ++mt)
#pragma unroll
            for (int nt = 0; nt < 4; ++nt) {
                acc[mt][nt] = MFMA16(amh[mt], bnh[nt], acc[mt][nt]);
                acc[mt][nt] = MFMA16(amh[mt], bnl[nt], acc[mt][nt]);
                acc[mt][nt] = MFMA16(aml[mt], bnh[nt], acc[mt][nt]);
            }
    }

    // ---- fused epilogue; hb = head-aligned col base (multiple of 64)
    const int hb = n0 + wn * 64;
    if (hb < 1024 + 512) {
        // Q or K: rope with invf matching the old kernels' double-pow exactly
        float invf0 = (float)pow(10000.0, -(double)col / 32.0);
        float invf1 = (float)pow(10000.0, -(double)(16 + col) / 32.0);
        const int isK = (hb >= 1024);
        const int kvh = isK ? ((hb - 1024) >> 6) : 0;
#pragma unroll
        for (int mt = 0; mt < 4; ++mt)
#pragma unroll
            for (int r = 0; r < 4; ++r) {
                int row = m0 + wm * 64 + mt * 16 + quad * 4 + r;
                float p = (float)pos[row];
                float s0, c0, s1, c1;
                sincosf(p * invf0, &s0, &c0);
                sincosf(p * invf1, &s1, &c1);
                float x0 = acc[mt][0][r], y0 = acc[mt][2][r];
                float x1 = acc[mt][1][r], y1 = acc[mt][3][r];
                float oA = x0 * c0 - y0 * s0;   // d = col
                float oB = y0 * c0 + x0 * s0;   // d = col + 32
                float oC = x1 * c1 - y1 * s1;   // d = 16 + col
                float oD = y1 * c1 + x1 * s1;   // d = 48 + col
                if (!isK) {
                    size_t base = (size_t)row * 1024 + hb;
                    Qrope[base + col]      = oA;
                    Qrope[base + col + 32] = oB;
                    Qrope[base + col + 16] = oC;
                    Qrope[base + col + 48] = oD;
                } else {
                    int b = row >> 11, l = row & 2047;
                    size_t base = ((size_t)(b * KVH_ + kvh) * L_ + l) * DH_;
                    unsigned short h;
                    h = bf16rne(oA); KHp[base + col]      = h; KLp[base + col]      = bf16rne(oA - bf2f(h));
                    h = bf16rne(oB); KHp[base + col + 32] = h; KLp[base + col + 32] = bf16rne(oB - bf2f(h));
                    h = bf16rne(oC); KHp[base + col + 16] = h; KLp[base + col + 16] = bf16rne(oC - bf2f(h));
                    h = bf16rne(oD); KHp[base + col + 48] = h; KLp[base + col + 48] = bf16rne(oD - bf2f(h));
                }
            }
    } else {
        // V: bf16, transposed to VT[b][kvh][d][L]
        const int kvh = (hb - 1536) >> 6;
#pragma unroll
        for (int mt = 0; mt < 4; ++mt)
#pragma unroll
            for (int nt = 0; nt < 4; ++nt) {
                int d = nt * 16 + col;
                int row0 = m0 + wm * 64 + mt * 16 + quad * 4;
                int b = row0 >> 11, l = row0 & 2047;
                size_t base = ((size_t)(b * KVH_ + kvh) * DH_ + d) * L_ + l;
                us4 vv;
#pragma unroll
                for (int r = 0; r < 4; ++r) vv[r] = bf16rne(acc[mt][nt][r]);
                *(us4*)(VTp + base) = vv;
            }
    }
}

// ---------------------------------------------------------------------------
// Fused sparse attention (R22 structure, unchanged math): 8 waves / 16 q-rows
// (2 per wave), 2 blocks/CU, sequential dual middles sharing one
// 4x-replicated time-multiplexed hist. R23 deltas: Q read from Qrope
// (stride 1024); AO written to dedicated hi|lo ushort buffer (lda 2048).
// ---------------------------------------------------------------------------
__global__ __launch_bounds__(512, 4) void attn(
    const float* __restrict__ QR,
    const unsigned short* __restrict__ KH,
    const unsigned short* __restrict__ KL,
    const unsigned short* __restrict__ VT,
    unsigned short* __restrict__ AOus) {

    extern __shared__ __align__(16) unsigned char dynsm[];
    float* Sc = (float*)dynsm;                     // [16][1034] f32 = 66176B
    unsigned short* Pc = (unsigned short*)dynsm;   // [16][2072] us = 66304B (union)
    u32* hist = (u32*)dynsm;                       // [8][1024] u32 = 32768B (union)
    float* qtile  = (float*)(dynsm + 66304);       // [16][68] f32 = 4352B
    float* outred = (float*)(dynsm + 66304);       // union w/ qtile

    const int t = threadIdx.x;                     // 0..511
    const int lane = t & 63, w = t >> 6;           // w in [0,8)
    const int quad = lane >> 4, col = lane & 15;
    const int bid0 = blockIdx.x;
    const int bid  = (bid0 & 7) * 512 + (bid0 >> 3);
    const int l0  = (bid & 255) * 8;
    const int kvh = (bid >> 8) & 7;
    const int b   = bid >> 11;
    const int r0 = 2 * w, r1 = 2 * w + 1;

    // ---- load Q tile (16 rows = 8 l-pos x heads {2kvh, 2kvh+1})
    if (t < 256) {
        int q = t >> 4, d4 = (t & 15) * 4;
        *(float4*)&qtile[q * 68 + d4] =
            *(const float4*)(QR + (size_t)(b * L_ + l0 + (q & 7)) * 1024 +
                             (kvh * 2 + (q >> 3)) * DH_ + d4);
    }
    __syncthreads();

    // ---- build A-frags (hi/lo)
    union FR { s8v v; unsigned short u[8]; };
    FR ah[2], al[2];
#pragma unroll
    for (int ks = 0; ks < 2; ++ks)
#pragma unroll
        for (int i = 0; i < 8; ++i) {
            float x = qtile[col * 68 + ks * 32 + quad * 8 + i];
            unsigned short hi = bf16rne(x);
            ah[ks].u[i] = hi;
            al[ks].u[i] = bf16rne(x - bf2f(hi));
        }

    // ---- QK^T in 2 J-halves of 1024 cols
    const size_t slabK = (size_t)(b * KVH_ + kvh) * L_ * DH_;
    const unsigned short* khp = KH + slabK;
    const unsigned short* klp = KL + slabK;
    u32 ukA[32], ukB[32];

#pragma unroll
    for (int half = 0; half < 2; ++half) {
        if (half) __syncthreads();
#pragma unroll
        for (int tj = 0; tj < 8; ++tj) {
            int jl = w * 128 + tj * 16;
            int j0 = half * 1024 + jl;
            const unsigned short* kh8 = khp + (size_t)(j0 + col) * 64 + quad * 8;
            const unsigned short* kl8 = klp + (size_t)(j0 + col) * 64 + quad * 8;
            s8v bh0 = *(const s8v*)(kh8);
            s8v bh1 = *(const s8v*)(kh8 + 32);
            s8v bl0 = *(const s8v*)(kl8);
            s8v bl1 = *(const s8v*)(kl8 + 32);
            f4v c = {0.f, 0.f, 0.f, 0.f};
            c = MFMA16(ah[0].v, bh0, c);
            c = MFMA16(al[0].v, bh0, c);
            c = MFMA16(ah[0].v, bl0, c);
            c = MFMA16(ah[1].v, bh1, c);
            c = MFMA16(al[1].v, bh1, c);
            c = MFMA16(ah[1].v, bl1, c);
            c = c * 0.125f;
#pragma unroll
            for (int r = 0; r < 4; ++r)
                Sc[(quad * 4 + r) * 1034 + jl + col] = c[r];
        }
        __syncthreads();
        if (half == 0) {
            outred[t] = 0.f;
            outred[t + 512] = 0.f;
            if (t < 64) outred[1024 + t] = 0.f;
        }
#pragma unroll
        for (int i2 = 0; i2 < 16; ++i2) {
            ukA[half * 16 + i2] = fkey(Sc[r0 * 1034 + i2 * 64 + lane]);
            ukB[half * 16 + i2] = fkey(Sc[r1 * 1034 + i2 * 64 + lane]);
        }
    }
    __syncthreads();

    // ---- wave-local middle (norm + radix top-1024 + softmax), per row
    u32* hq = &hist[w * 1024];
    const int rep = lane & 3;
    auto middle = [&](u32 (&uk)[32]) -> float {
        u32 ulo = 0xFFFFFFFFu, uhi = 0u;
#pragma unroll
        for (int i = 0; i < 32; ++i) {
            u32 u = uk[i];
            ulo = (u < ulo) ? u : ulo;
            uhi = (u > uhi) ? u : uhi;
        }
        for (int off = 1; off < 64; off <<= 1) {
            u32 ol = (u32)__shfl_xor((int)ulo, off);
            u32 oh = (u32)__shfl_xor((int)uhi, off);
            ulo = (ol < ulo) ? ol : ulo;
            uhi = (oh > uhi) ? oh : uhi;
        }
        const float mrow = fkeyinv(uhi);
        const int sh = __clz((int)((uhi - ulo) | 1u));
#pragma unroll
        for (int i = 0; i < 32; ++i) uk[i] = (uk[i] - ulo) << sh;

        u32 pf = 0u, kq = (u32)TOPK_, ng = 0u, geq = 0u;
        for (int pass = 0; pass < 4; ++pass) {
            int shift = 24 - 8 * pass;
#pragma unroll
            for (int i = 0; i < 4; ++i)
                *(uint4*)&hq[i * 256 + lane * 4] = make_uint4(0u, 0u, 0u, 0u);
            u32 pm = pass ? (0xFFFFFFFFu << (shift + 8)) : 0u;
#pragma unroll
            for (int i = 0; i < 32; ++i) {
                u32 u = uk[i];
                if ((u & pm) == pf) {
                    u32 d = (u >> shift) & 255u;
                    atomicAdd(&hq[(d & 3) * 256 + (d >> 2) * 4 + rep], 1u);
                }
            }
            u32 hb_[4];
            u32 s4 = 0u;
#pragma unroll
            for (int bb = 0; bb < 4; ++bb) {
                uint4 hv = *(const uint4*)&hq[bb * 256 + lane * 4];
                hb_[bb] = hv.x + hv.y + hv.z + hv.w;
                s4 += hb_[bb];
            }
            u32 v = s4;
            for (int off = 1; off < 64; off <<= 1) {
                u32 tmp = __shfl_down(v, off);
                if (lane + off < 64) v += tmp;
            }
            u32 g = v - s4;
            u32 mydig = 0u, myk = 0u, myng = 0u, myhb = 0u;
            bool found = false;
#pragma unroll
            for (int bb = 3; bb >= 0; --bb) {
                u32 hb = hb_[bb];
                if (hb && g < kq && kq <= g + hb) {
                    found = true;
                    mydig = (u32)(4 * lane + bb);
                    myk   = kq - g;
                    myng  = ng + g;
                    myhb  = hb;
                }
                g += hb;
            }
            u64 fm = __ballot(found);
            int src = (int)__builtin_ctzll(fm);
            pf |= ((u32)__shfl((int)mydig, src)) << shift;
            kq  = (u32)__shfl((int)myk,  src);
            ng  = (u32)__shfl((int)myng, src);
            u32 hbs = (u32)__shfl((int)myhb, src);
            if (kq == hbs) { geq = 1u; break; }
        }

        const u32 uth = pf;
        u32 selm = 0u;
        if (geq) {
#pragma unroll
            for (int i = 0; i < 32; ++i)
                if (uk[i] >= uth) selm |= 1u << i;
        } else {
            const u32 quota = (u32)TOPK_ - ng;
            u32 eqm = 0u;
#pragma unroll
            for (int i = 0; i < 32; ++i) {
                u32 u = uk[i];
                if (u > uth) selm |= 1u << i;
                else if (u == uth) eqm |= 1u << i;
            }
            u32 ec = (u32)__builtin_popcount(eqm);
            for (int off = 1; off < 64; off <<= 1) ec += __shfl_xor(ec, off);
            if (ec == quota) {
                selm |= eqm;
            } else {
                u32 base = 0;
                u64 lmask = ((u64)1 << lane) - 1;
#pragma unroll
                for (int i = 0; i < 32; ++i) {
                    u64 mm = __ballot((eqm >> i) & 1u);
                    if ((eqm >> i) & 1u) {
                        u32 rk = base + (u32)__builtin_popcountll(mm & lmask);
                        if (rk < quota) selm |= 1u << i;
                    }
                    base += (u32)__builtin_popcountll(mm);
                }
            }
        }

        float z = 0.f;
#pragma unroll
        for (int i = 0; i < 32; ++i) {
            float vv = fkeyinv((uk[i] >> sh) + ulo);
            float e = ((selm >> i) & 1u) ? __expf(vv - mrow) : 0.f;
            uk[i] = __float_as_uint(e);
            z += e;
        }
        for (int off = 1; off < 64; off <<= 1) z += __shfl_xor(z, off);
        return 1.0f / z;
    };

    float invZA = middle(ukA);
    float invZB = middle(ukB);

    // ---- prefetch kc0 V tiles
    const unsigned short* vt = VT + (size_t)(b * KVH_ + kvh) * DH_ * L_;
    const int jb0 = w * 256 + quad * 8;
    s8v pv0 = *(const s8v*)(vt + (size_t)( 0 + col) * L_ + jb0);
    s8v pv1 = *(const s8v*)(vt + (size_t)(16 + col) * L_ + jb0);
    s8v pv2 = *(const s8v*)(vt + (size_t)(32 + col) * L_ + jb0);
    s8v pv3 = *(const s8v*)(vt + (size_t)(48 + col) * L_ + jb0);

    __syncthreads();                     // all hist use done; Pc region free

    // ---- P -> Pc (bf16, invZ folded); rows r0, r1
#pragma unroll
    for (int i = 0; i < 32; ++i) {
        int jp = 1024 * (i >> 4) + 64 * (i & 15) + lane;
        Pc[r0 * 2072 + jp] = bf16rne(__uint_as_float(ukA[i]) * invZA);
        Pc[r1 * 2072 + jp] = bf16rne(__uint_as_float(ukB[i]) * invZB);
    }
    __syncthreads();

    // ---- PV via MFMA; wave w covers j in [256w, 256w+256) in 8 sub-chunks
    f4v acc0 = {0.f, 0.f, 0.f, 0.f}, acc1 = acc0, acc2 = acc0, acc3 = acc0;
    {
        s8v ap = *(const s8v*)&Pc[col * 2072 + jb0];
        acc0 = MFMA16(ap, pv0, acc0);
        acc1 = MFMA16(ap, pv1, acc1);
        acc2 = MFMA16(ap, pv2, acc2);
        acc3 = MFMA16(ap, pv3, acc3);
    }
#pragma unroll
    for (int kc = 1; kc < 8; ++kc) {
        int jb = w * 256 + kc * 32 + quad * 8;
        s8v ap = *(const s8v*)&Pc[col * 2072 + jb];
        s8v v0 = *(const s8v*)(vt + (size_t)( 0 + col) * L_ + jb);
        s8v v1 = *(const s8v*)(vt + (size_t)(16 + col) * L_ + jb);
        s8v v2 = *(const s8v*)(vt + (size_t)(32 + col) * L_ + jb);
        s8v v3 = *(const s8v*)(vt + (size_t)(48 + col) * L_ + jb);
        acc0 = MFMA16(ap, v0, acc0);
        acc1 = MFMA16(ap, v1, acc1);
        acc2 = MFMA16(ap, v2, acc2);
        acc3 = MFMA16(ap, v3, acc3);
    }

    // ---- cross-wave PV reduction + store as bf16 hi/lo (AO lda 2048)
#pragma unroll
    for (int r = 0; r < 4; ++r) {
        atomicAdd(&outred[(quad * 4 + r) * 68 +  0 + col], acc0[r]);
        atomicAdd(&outred[(quad * 4 + r) * 68 + 16 + col], acc1[r]);
        atomicAdd(&outred[(quad * 4 + r) * 68 + 32 + col], acc2[r]);
        atomicAdd(&outred[(quad * 4 + r) * 68 + 48 + col], acc3[r]);
    }
    __syncthreads();
    if (t < 256) {
        int q = t >> 4, d4 = (t & 15) * 4;
        float4 o = *(float4*)&outred[q * 68 + d4];
        size_t m = (size_t)(b * L_ + l0 + (q & 7));
        int n = (kvh * 2 + (q >> 3)) * DH_ + d4;
        float x[4] = {o.x, o.y, o.z, o.w};
        us4 hv, lv;
#pragma unroll
        for (int i = 0; i < 4; ++i) {
            unsigned short hi = bf16rne(x[i]);
            hv[i] = hi;
            lv[i] = bf16rne(x[i] - bf2f(hi));
        }
        *(us4*)(AOus + m * 2048 + n) = hv;
        *(us4*)(AOus + m * 2048 + 1024 + n) = lv;
    }
}

// ---------------------------------------------------------------------------
extern "C" void kernel_launch(void* const* d_in, const int* in_sizes, int n_in,
                              void* d_out, int out_size, void* d_ws, size_t ws_size,
                              hipStream_t stream) {
    const float* hs = (const float*)d_in[0];
    const float* wq = (const float*)d_in[1];
    const float* wk = (const float*)d_in[2];
    const float* wv = (const float*)d_in[3];
    const float* wo = (const float*)d_in[4];
    const int*  pos = (const int*)d_in[5];

    float* ws = (float*)d_ws;
    const size_t M1 = 1u << 20;
    float* Qrope = ws;                          // [0, 4M) fp32 [4096][1024]
    // hs pre-split (dead after gemm_qkv) overlays AO (written by attn later)
    unsigned short* hsH  = (unsigned short*)(ws + 4 * M1);   // [4096][1024]
    unsigned short* hsL  = (unsigned short*)(ws + 6 * M1);
    unsigned short* AOus = (unsigned short*)(ws + 4 * M1);   // [4096][2048] hi|lo
    unsigned short* QKVWh = (unsigned short*)(ws +  8 * M1); // [2048][1024]
    unsigned short* QKVWl = (unsigned short*)(ws +  9 * M1);
    unsigned short* WoH   = (unsigned short*)(ws + 10 * M1);
    unsigned short* WoL   = (unsigned short*)(ws + 10 * M1 + M1 / 2);
    unsigned short* KH    = (unsigned short*)(ws + 11 * M1);
    unsigned short* KL    = (unsigned short*)(ws + 12 * M1);
    unsigned short* VT    = (unsigned short*)(ws + 13 * M1);
    float* out = (float*)d_out;

    static bool attr_set = false;
    if (!attr_set) {
        hipFuncSetAttribute((const void*)attn,
                            hipFuncAttributeMaxDynamicSharedMemorySize, 70656);
        attr_set = true;
    }

    dim3 blk(256);
    prep_wt_all<<<dim3(16, 48), blk, 0, stream>>>(wq, wk, wv, wo,
                                                  QKVWh, QKVWl, WoH, WoL);
    split_a<<<dim3(4096), blk, 0, stream>>>(hs, hsH, hsL);
    gemm_qkv<<<dim3(32, 16), blk, 0, stream>>>(hsH, hsL, QKVWh, QKVWl, pos,
                                               Qrope, KH, KL, VT);
    attn<<<dim3(4096), dim3(512), 70656, stream>>>(Qrope, KH, KL, VT, AOus);
    gemm_bf<<<dim3(32, 8), blk, 0, stream>>>(AOus, AOus + 1024, 2048,
                                             WoH, WoL, out, 1024, 1024);
}